// Round 5
// baseline (808.848 us; speedup 1.0000x reference)
//
#include <hip/hip_runtime.h>
#include <hip/hip_bf16.h>

// ---- problem constants (match reference) ----
#define TS 8192     // tokens S
#define TM 4096     // model dim M
#define TE 64       // experts E
#define TCAP 128    // capacity
#define KS 8        // split-K chunks
#define KCHUNK (TM / KS)      // 512
#define BK 16
#define NTILE (KCHUNK / BK)   // 32
#define BM 128                // tokens per gemm tile
#define GEMM_BLOCKS 512       // 64 tiles * 8 k-chunks
#define K1_GRID 2048
#define NFILL (K1_GRID - GEMM_BLOCKS)   // 1536

constexpr size_t CWsz = (size_t)TS * TE * TCAP;   // 67108864 per big output
constexpr size_t NOUT = 1 + 2 * CWsz + TE;        // 134217793 floats
constexpr size_t NF4  = (NOUT - 1) / 4;           // 33554448 float4s
constexpr size_t FSTRIDE = (size_t)NFILL * 256;

typedef float v4f __attribute__((ext_vector_type(4)));

// ===== K1: NT zero-fill (1536 blocks) || split-K GEMM (512 blocks), with
// per-tile last-arriver softmax+argmax fused (split-K fixup pattern: the
// 8th block to finish a 128-token tile reduces the 8 partials in fixed
// order p=0..7 -> deterministic, no grid sync, no co-residency needed).
__global__ __launch_bounds__(256) void k1_gemm_fill_softmax(
    const float* __restrict__ x, const float* __restrict__ wg,
    float* __restrict__ part, float* __restrict__ gate1, int* __restrict__ idx1,
    float* __restrict__ me, int* __restrict__ tilecnt, float* __restrict__ out) {
  const int tid = threadIdx.x;
  const int v = (int)((blockIdx.x * 5u) & (K1_GRID - 1));  // bijective swizzle

  __shared__ float As[BK][132];   // all LDS access <=2-way alias (free)
  __shared__ float Ws[BK][68];
  __shared__ int lastf;

  if (v >= GEMM_BLOCKS) {
    // ---- fill role: stream zeros over d_out, cache-bypassing ----
    const int fid = v - GEMM_BLOCKS;
    const v4f z = {0.f, 0.f, 0.f, 0.f};
    v4f* o4 = (v4f*)out;
    for (size_t i = (size_t)fid * 256 + tid; i < NF4; i += FSTRIDE)
      __builtin_nontemporal_store(z, &o4[i]);
    return;
  }

  // ---- gemm role: 128 tok x 64 e partial over one 512-wide k-chunk ----
  const int tile = v & 63;
  const int t0 = tile * BM;
  const int k0 = (v >> 6) * KCHUNK;
  const int tg = tid >> 3;      // 4 tokens per thread
  const int eg = tid & 7;       // 8 experts per thread

  float acc[4][8] = {};
  float4 ra[2], rw;
  auto load = [&](int kt) {
    const int kb = k0 + kt * BK;
#pragma unroll
    for (int i = 0; i < 2; i++) {
      int idx = tid + 256 * i;
      int tok = idx >> 2, c4 = idx & 3;
      ra[i] = *(const float4*)&x[(size_t)(t0 + tok) * TM + kb + 4 * c4];
    }
    { int e = tid >> 2, c4 = tid & 3;
      rw = *(const float4*)&wg[(size_t)e * TM + kb + 4 * c4]; }
  };
  load(0);
  for (int kt = 0; kt < NTILE; kt++) {
#pragma unroll
    for (int i = 0; i < 2; i++) {
      int idx = tid + 256 * i;
      int tok = idx >> 2, c4 = idx & 3;
      As[4 * c4 + 0][tok] = ra[i].x; As[4 * c4 + 1][tok] = ra[i].y;
      As[4 * c4 + 2][tok] = ra[i].z; As[4 * c4 + 3][tok] = ra[i].w;
    }
    { int e = tid >> 2, c4 = tid & 3;
      Ws[4 * c4 + 0][e] = rw.x; Ws[4 * c4 + 1][e] = rw.y;
      Ws[4 * c4 + 2][e] = rw.z; Ws[4 * c4 + 3][e] = rw.w; }
    __syncthreads();
    if (kt + 1 < NTILE) load(kt + 1);   // reg prefetch overlaps MACs
#pragma unroll
    for (int k = 0; k < BK; k++) {
      float4 a  = *(const float4*)&As[k][tg * 4];
      float4 b0 = *(const float4*)&Ws[k][eg * 8];
      float4 b1 = *(const float4*)&Ws[k][eg * 8 + 4];
      float av[4] = {a.x, a.y, a.z, a.w};
      float bv[8] = {b0.x, b0.y, b0.z, b0.w, b1.x, b1.y, b1.z, b1.w};
#pragma unroll
      for (int i = 0; i < 4; i++)
#pragma unroll
        for (int j = 0; j < 8; j++) acc[i][j] += av[i] * bv[j];
    }
    __syncthreads();
  }
  float* dst = part + (size_t)(v >> 6) * TS * TE;
#pragma unroll
  for (int i = 0; i < 4; i++) {
    int tok = t0 + tg * 4 + i;
    *(float4*)&dst[(size_t)tok * TE + eg * 8] =
        make_float4(acc[i][0], acc[i][1], acc[i][2], acc[i][3]);
    *(float4*)&dst[(size_t)tok * TE + eg * 8 + 4] =
        make_float4(acc[i][4], acc[i][5], acc[i][6], acc[i][7]);
  }

  // ---- split-K completion: last arriver does this tile's softmax ----
  __threadfence();   // release partial writes (device scope, cross-XCD)
  if (tid == 0) lastf = (atomicAdd(&tilecnt[tile], 1) == KS - 1) ? 1 : 0;
  __syncthreads();
  if (!lastf) return;
  __threadfence();   // acquire other blocks' partials

  const int w = tid >> 6, lane = tid & 63;   // lane = expert
  float mesum = 0.0f;
  for (int it = 0; it < 32; it++) {
    const int s = t0 + w * 32 + it;
    float logit = 0.0f;
#pragma unroll
    for (int p = 0; p < KS; p++)
      logit += part[((size_t)p * TS + s) * TE + lane];  // fixed order: determ.
    // wave argmax, first-index tie-break (matches jnp.argmax)
    float mv = logit; int mi = lane;
#pragma unroll
    for (int off = 32; off; off >>= 1) {
      float ov = __shfl_xor(mv, off);
      int oi = __shfl_xor(mi, off);
      if (ov > mv || (ov == mv && oi < mi)) { mv = ov; mi = oi; }
    }
    float ex = expf(logit - mv);
    float sum = ex;
#pragma unroll
    for (int off = 32; off; off >>= 1) sum += __shfl_xor(sum, off);
    float g = ex / sum;
    mesum += g;
    if (lane == mi) { gate1[s] = g; idx1[s] = mi; }
  }
  float* lds = &As[0][0];     // safe: all threads past last loop barrier
  lds[w * 64 + lane] = mesum;
  __syncthreads();
  if (w == 0)
    atomicAdd(&me[lane], lds[lane] + lds[64 + lane] + lds[128 + lane] + lds[192 + lane]);
}

// ===== K2: capacity rank (token order) + direct scatter + last-block
// l_aux/exp_counts. 64 blocks (1/expert) x 4 waves. Token ownership is
// exclusive -> scatter race-free. =====
__global__ __launch_bounds__(256) void k2_rank_scatter_laux(
    const int* __restrict__ idx1, const float* __restrict__ gate1,
    const float* __restrict__ me, int* __restrict__ cnts, int* __restrict__ done,
    float* __restrict__ out) {
  const int e = blockIdx.x;
  const int w = threadIdx.x >> 6, lane = threadIdx.x & 63;
  const int s0 = w * (TS / 4);
  __shared__ int wcnt[4];
  __shared__ int lastf;

  int cnt = 0;
  for (int c = 0; c < TS / 4 / 64; c++)
    cnt += __popcll(__ballot(idx1[s0 + c * 64 + lane] == e));
  if (lane == 0) wcnt[w] = cnt;
  __syncthreads();
  int base = 0;
  for (int j = 0; j < w; j++) base += wcnt[j];

  for (int c = 0; c < TS / 4 / 64; c++) {
    int s = s0 + c * 64 + lane;
    bool m = (idx1[s] == e);
    unsigned long long mask = __ballot(m);
    if (m) {
      int p = base + __popcll(mask & ((1ull << lane) - 1ull));
      if (p < TCAP) {
        size_t off = 1 + ((size_t)s * TE + e) * (size_t)TCAP + (size_t)p;
        out[off] = gate1[s];          // combine_weights
        out[off + CWsz] = 1.0f;       // dispatch_mask
      }
    }
    base += __popcll(mask);
  }
  if (w == 3 && lane == 0) {
    cnts[e] = base;                   // pre-drop exp_counts
    __threadfence();                  // release before signaling
    lastf = (atomicAdd(done, 1) == TE - 1) ? 1 : 0;
  }
  __syncthreads();
  if (lastf && w == 0) {
    __threadfence();                  // acquire all cnts
    int c = cnts[lane];
    float vv = (me[lane] / (float)TS) * ((float)c / (float)TS);
    float sum = vv;
#pragma unroll
    for (int off = 32; off; off >>= 1) sum += __shfl_xor(sum, off);
    if (lane == 0) out[0] = sum * (float)TE;
    out[1 + 2 * CWsz + lane] = (float)c;   // incl. final element NOUT-1
  }
}

extern "C" void kernel_launch(void* const* d_in, const int* in_sizes, int n_in,
                              void* d_out, int out_size, void* d_ws, size_t ws_size,
                              hipStream_t stream) {
  const float* x  = (const float*)d_in[0];
  const float* wg = (const float*)d_in[1];
  float* out = (float*)d_out;

  float* part    = (float*)d_ws;                    // [KS][S][E] 16.8 MB
  float* gate1   = part + (size_t)KS * TS * TE;     // [S]
  int*   idx1    = (int*)(gate1 + TS);              // [S]
  float* me      = (float*)(idx1 + TS);             // [E]
  int*   tilecnt = (int*)(me + TE);                 // [64]
  int*   done    = tilecnt + TE;                    // [1]
  int*   cnts    = done + 1;                        // [E] (written before read)

  // zero the atomic counters + me accumulator (ws is poisoned 0xAA)
  hipMemsetAsync(me, 0, (TE + TE + 1) * sizeof(int), stream);

  k1_gemm_fill_softmax<<<K1_GRID, 256, 0, stream>>>(x, wg, part, gate1, idx1,
                                                    me, tilecnt, out);
  k2_rank_scatter_laux<<<TE, 256, 0, stream>>>(idx1, gate1, me, cnts, done, out);
}

// Round 6
// 759.231 us; speedup vs baseline: 1.0654x; 1.0654x over previous
//
#include <hip/hip_runtime.h>
#include <hip/hip_bf16.h>

// ---- problem constants (match reference) ----
#define TS 8192     // tokens S
#define TM 4096     // model dim M
#define TE 64       // experts E
#define TCAP 128    // capacity
#define BK 16
#define NTILE (TM / BK)       // 256 k-tiles (full K per block; no split-K)
#define BM 32                 // tokens per gemm block
#define GEMM_BLOCKS (TS / BM) // 256
#define K1_GRID 1024
#define NFILL (K1_GRID - GEMM_BLOCKS)   // 768

constexpr size_t CWsz = (size_t)TS * TE * TCAP;   // 67108864 per big output
constexpr size_t NOUT = 1 + 2 * CWsz + TE;        // 134217793 floats
constexpr size_t NF4  = (NOUT - 1) / 4;           // 33554448 float4s (covers out[0..NOUT-2])
constexpr size_t FSTRIDE = (size_t)NFILL * 256;   // fill grid-stride in float4s

typedef float v4f __attribute__((ext_vector_type(4)));

// ===== K1: NT zero-fill of d_out (768 blocks) || full-K GEMM + in-block
// softmax/argmax (256 blocks, 32 tokens each). No split-K -> no part[]
// round-trip, no atomics, no fences. Softmax input lives in LDS. =====
__global__ __launch_bounds__(256, 4) void k1_gemm_fill_softmax(
    const float* __restrict__ x, const float* __restrict__ wg,
    float* __restrict__ gate1, int* __restrict__ idx1,
    float* __restrict__ mepart, float* __restrict__ out) {
  const int tid = threadIdx.x;
  const int v = (int)((blockIdx.x * 5u) & (K1_GRID - 1));  // bijective swizzle

  // one buffer, two lives: [As 16x34 | Ws 16x68] during GEMM (1632 floats),
  // then S 32x65 (2080) + S2 4x64 (256) for softmax. 2336 floats = 9344 B.
  __shared__ float smem[2336];

  if (v >= GEMM_BLOCKS) {
    // ---- fill role: stream zeros over d_out, cache-bypassing ----
    const int fid = v - GEMM_BLOCKS;
    const v4f z = {0.f, 0.f, 0.f, 0.f};
    v4f* o4 = (v4f*)out;
    for (size_t i = (size_t)fid * 256 + tid; i < NF4; i += FSTRIDE)
      __builtin_nontemporal_store(z, &o4[i]);
    return;
  }

  // ---- gemm role: 32 tokens x 64 experts, full K=4096 ----
  float (*As)[34] = (float(*)[34])smem;          // [k][token], writes/reads <=2-way
  float (*Ws)[68] = (float(*)[68])(smem + 544);  // [k][expert], verified <=2-way
  const int tile = v;
  const int t0 = tile * BM;
  const int tg = tid >> 3;      // token 0..31
  const int eg = tid & 7;       // expert group: 8 experts

  float acc[8] = {};
  float2 ra; float4 rw;
  auto load = [&](int kt) {
    const int kb = kt * BK;
    ra = *(const float2*)&x[(size_t)(t0 + tg) * TM + kb + 2 * (tid & 7)];
    rw = *(const float4*)&wg[(size_t)(tid >> 2) * TM + kb + 4 * (tid & 3)];
  };
  load(0);
  for (int kt = 0; kt < NTILE; kt++) {
    { const int c2 = tid & 7;
      As[2 * c2 + 0][tg] = ra.x; As[2 * c2 + 1][tg] = ra.y; }
    { const int e = tid >> 2, c4 = tid & 3;
      Ws[4 * c4 + 0][e] = rw.x; Ws[4 * c4 + 1][e] = rw.y;
      Ws[4 * c4 + 2][e] = rw.z; Ws[4 * c4 + 3][e] = rw.w; }
    __syncthreads();
    if (kt + 1 < NTILE) load(kt + 1);   // reg prefetch overlaps MACs
#pragma unroll
    for (int k = 0; k < BK; k++) {
      float a  = As[k][tg];
      float4 b0 = *(const float4*)&Ws[k][eg * 8];
      float4 b1 = *(const float4*)&Ws[k][eg * 8 + 4];
      acc[0] += a * b0.x; acc[1] += a * b0.y; acc[2] += a * b0.z; acc[3] += a * b0.w;
      acc[4] += a * b1.x; acc[5] += a * b1.y; acc[6] += a * b1.z; acc[7] += a * b1.w;
    }
    __syncthreads();
  }

  // ---- in-block softmax/argmax: logits -> LDS (stride 65: 2-way max) ----
  float* S = smem;            // [32][65]
  float* S2 = smem + 2080;    // [4][64] per-wave me partials
#pragma unroll
  for (int j = 0; j < 8; j++) S[tg * 65 + eg * 8 + j] = acc[j];
  __syncthreads();

  const int w = tid >> 6, lane = tid & 63;   // lane = expert
  float esum = 0.0f;
  for (int i = 0; i < 8; i++) {
    const int t = w * 8 + i;
    float logit = S[t * 65 + lane];
    // wave argmax, first-index tie-break (matches jnp.argmax)
    float mv = logit; int mi = lane;
#pragma unroll
    for (int off = 32; off; off >>= 1) {
      float ov = __shfl_xor(mv, off);
      int oi = __shfl_xor(mi, off);
      if (ov > mv || (ov == mv && oi < mi)) { mv = ov; mi = oi; }
    }
    float ex = expf(logit - mv);
    float sum = ex;
#pragma unroll
    for (int off = 32; off; off >>= 1) sum += __shfl_xor(sum, off);
    float g = ex / sum;
    esum += g;
    if (lane == mi) { gate1[t0 + t] = g; idx1[t0 + t] = mi; }
  }
  S2[w * 64 + lane] = esum;
  __syncthreads();
  if (w == 0)
    mepart[(size_t)tile * TE + lane] =
        S2[lane] + S2[64 + lane] + S2[128 + lane] + S2[192 + lane];
}

// ===== K2: me reduce + capacity rank (token order) + direct scatter.
// 64 blocks (1/expert) x 4 waves. Token ownership exclusive -> race-free. =====
__global__ __launch_bounds__(256) void k2_rank_scatter(
    const int* __restrict__ idx1, const float* __restrict__ gate1,
    const float* __restrict__ mepart, float* __restrict__ mefin,
    int* __restrict__ cnts, float* __restrict__ out) {
  const int e = blockIdx.x;
  const int w = threadIdx.x >> 6, lane = threadIdx.x & 63;
  __shared__ float red[256];
  __shared__ int wcnt[4];

  // me[e] = sum over 256 tiles (deterministic tree)
  red[threadIdx.x] = mepart[(size_t)threadIdx.x * TE + e];
  __syncthreads();
  for (int o = 128; o; o >>= 1) {
    if (threadIdx.x < o) red[threadIdx.x] += red[threadIdx.x + o];
    __syncthreads();
  }
  if (threadIdx.x == 0) mefin[e] = red[0];

  // rank pass A: per-wave-range counts
  const int s0 = w * (TS / 4);
  int cnt = 0;
  for (int c = 0; c < TS / 4 / 64; c++)
    cnt += __popcll(__ballot(idx1[s0 + c * 64 + lane] == e));
  if (lane == 0) wcnt[w] = cnt;
  __syncthreads();
  int base = 0;
  for (int j = 0; j < w; j++) base += wcnt[j];

  // pass B: exact token-order rank + scatter (L2-hot)
  for (int c = 0; c < TS / 4 / 64; c++) {
    int s = s0 + c * 64 + lane;
    bool m = (idx1[s] == e);
    unsigned long long mask = __ballot(m);
    if (m) {
      int p = base + __popcll(mask & ((1ull << lane) - 1ull));
      if (p < TCAP) {
        size_t off = 1 + ((size_t)s * TE + e) * (size_t)TCAP + (size_t)p;
        out[off] = gate1[s];          // combine_weights
        out[off + CWsz] = 1.0f;       // dispatch_mask
      }
    }
    base += __popcll(mask);
  }
  if (w == 3 && lane == 0) cnts[e] = base;   // pre-drop exp_counts
}

// ===== K3: l_aux + exp_counts tail (1 block, 64 threads) =====
__global__ void k3_laux(const float* __restrict__ mefin, const int* __restrict__ cnts,
                        float* __restrict__ out) {
  const int lane = threadIdx.x;
  int c = cnts[lane];
  float vv = (mefin[lane] / (float)TS) * ((float)c / (float)TS);
  float sum = vv;
#pragma unroll
  for (int off = 32; off; off >>= 1) sum += __shfl_xor(sum, off);
  if (lane == 0) out[0] = sum * (float)TE;
  out[1 + 2 * CWsz + lane] = (float)c;   // includes final element NOUT-1
}

extern "C" void kernel_launch(void* const* d_in, const int* in_sizes, int n_in,
                              void* d_out, int out_size, void* d_ws, size_t ws_size,
                              hipStream_t stream) {
  const float* x  = (const float*)d_in[0];
  const float* wg = (const float*)d_in[1];
  float* out = (float*)d_out;

  float* gate1  = (float*)d_ws;                     // [S]
  int*   idx1   = (int*)(gate1 + TS);               // [S]
  float* mepart = (float*)(idx1 + TS);              // [256][E]
  float* mefin  = mepart + (size_t)GEMM_BLOCKS * TE;// [E]
  int*   cnts   = (int*)(mefin + TE);               // [E]

  k1_gemm_fill_softmax<<<K1_GRID, 256, 0, stream>>>(x, wg, gate1, idx1, mepart, out);
  k2_rank_scatter<<<TE, 256, 0, stream>>>(idx1, gate1, mepart, mefin, cnts, out);
  k3_laux<<<1, 64, 0, stream>>>(mefin, cnts, out);
}